// Round 1
// 499.648 us; speedup vs baseline: 1.2983x; 1.2983x over previous
//
#include <hip/hip_runtime.h>
#include <stdint.h>

// Problem dims (fixed by reference)
#define TOKENS 8192
#define DIN    4096
#define DOUT   4096

typedef short bf16x8 __attribute__((ext_vector_type(8)));  // 8 bf16 = 4 VGPRs
typedef float f32x4  __attribute__((ext_vector_type(4)));  // MFMA 16x16 accum

// ---- fp32 -> bf16 round-to-nearest-even (inputs finite) ----
__device__ __forceinline__ unsigned short f2bf(float f) {
    union { float f; unsigned int u; } v; v.f = f;
    return (unsigned short)((v.u + 0x7fffu + ((v.u >> 16) & 1u)) >> 16);
}

// ---- ternary int {-1,0,1} -> bf16 bit pattern (2 selects, no float math) ----
__device__ __forceinline__ unsigned short tern2bf(int v) {
    return v == 0 ? (unsigned short)0u
                  : (v > 0 ? (unsigned short)0x3F80u : (unsigned short)0xBF80u);
}

// ---- async global->LDS, 16B/lane; LDS dest = wave-uniform base + lane*16 ----
__device__ __forceinline__ void gload_lds16(const unsigned short* g, unsigned short* l) {
    __builtin_amdgcn_global_load_lds(
        (const __attribute__((address_space(1))) unsigned int*)g,
        (__attribute__((address_space(3))) unsigned int*)l,
        16, 0, 0);
}

// ================= fused prologue: one kernel, two jobs =================
// blocks [0, 1024):   W int32 [K][N] -> Wt bf16 [N][K], 256k x 64n LDS tiles.
// blocks [1024, 3072): x fp32 -> bf16, 2x float4 in -> 1x 16B store out.
#define WBLKS 1024
#define XBLKS 2048

__global__ __launch_bounds__(256) void fused_cvt(
    const float* __restrict__ x, const int* __restrict__ W,
    unsigned short* __restrict__ xb, unsigned short* __restrict__ Wt) {
    __shared__ unsigned short lds[64][264];   // [n_local][k_local], pitch 264
    const int t = threadIdx.x;

    if (blockIdx.x < WBLKS) {
        // ---- W transpose part: tile k0..k0+255, n0..n0+63 ----
        const int b  = blockIdx.x;
        const int k0 = (b >> 6) * 256;        // 16 k-tiles
        const int n0 = (b & 63) * 64;         // 64 n-tiles
        const int nl = 4 * (t & 15);          // n_local base this thread fills
#pragma unroll
        for (int it = 0; it < 16; ++it) {
            const int r = (t >> 4) + 16 * it; // k_local
            int4 v = *(const int4*)&W[(size_t)(k0 + r) * DOUT + n0 + nl];
            lds[nl + 0][r] = tern2bf(v.x);
            lds[nl + 1][r] = tern2bf(v.y);
            lds[nl + 2][r] = tern2bf(v.z);
            lds[nl + 3][r] = tern2bf(v.w);
        }
        __syncthreads();
        const int n = t >> 2;                 // 0..63
        const int s = t & 3;
        unsigned short* drow = Wt + (size_t)(n0 + n) * DIN + k0;
#pragma unroll
        for (int u = 0; u < 8; ++u) {
            const int k = u * 32 + s * 8;     // lanes 0-3 cover 64B contiguous
            *(uint4*)&drow[k] = *(const uint4*)&lds[n][k];
        }
    } else {
        // ---- x convert part: 8 chunks of 8 floats per thread ----
        const int b2 = blockIdx.x - WBLKS;    // 0..2047
        const int stride = XBLKS * 256;       // chunks per sweep
        int c = b2 * 256 + t;
        const float4* x4 = (const float4*)x;
        uint4* o = (uint4*)xb;                // 8 bf16 = 16B per chunk
#pragma unroll
        for (int j = 0; j < 8; ++j, c += stride) {
            float4 a = x4[2 * c];
            float4 bvec = x4[2 * c + 1];
            uint4 p;
            p.x = (unsigned)f2bf(a.x)    | ((unsigned)f2bf(a.y) << 16);
            p.y = (unsigned)f2bf(a.z)    | ((unsigned)f2bf(a.w) << 16);
            p.z = (unsigned)f2bf(bvec.x) | ((unsigned)f2bf(bvec.y) << 16);
            p.w = (unsigned)f2bf(bvec.z) | ((unsigned)f2bf(bvec.w) << 16);
            o[c] = p;
        }
    }
}

// ================= main GEMM: 256x256 tile, BK=64, 8-phase schedule =================
// C[M][N] = A[M][K] * Bt[N][K]^T, bf16 inputs, fp32 accum.
// 512 threads = 8 waves in a 2(M) x 4(N) grid; each wave owns a 128x64 output tile
// (8 M-frags x 4 N-frags of 16x16, acc = 32 x f32x4 = 128 VGPR).
// LDS: sA[2][256][64] + sB[2][256][64] bf16 = 128 KiB (double-buffered K-tiles).
//
// LDS swizzle (T2, rule #21 both-sides): linear LDS slot (row, q') holds global
// k-quad q = q' ^ (row&7). Staging pre-swizzles the GLOBAL source per lane
// (gload_lds dest stays linear: base + lane*16B); ds_read applies the same XOR.
// Worst-case bank aliasing = 2-way (free).
//
// 8 phases per loop iter = 2 K-tiles (kt, kt+64). Phase = quadrant (2 M-frags x
// 4 N-frags x K=64 -> 16 MFMA). B-frags loaded once per K-tile (quadrant 0).
// Staging ledger (half-tile = 128 rows x 64 k = 2 gload_lds/wave), one per phase:
//   p0: sA[1].h0 @kt+64   p1: sA[1].h1 @kt+64    (A of 2nd tile, read p4-p7)
//   p2: sB[0].h0 @kt+128  p3: sB[0].h1 @kt+128 + vmcnt(4)
//   p4: sA[0].h0 @kt+128  p5: sA[0].h1 @kt+128
//   p6: sB[1].h0 @kt+192  p7: sB[1].h1 @kt+192 + vmcnt(4)
// Safety: every overwrite is issued only after the phase-end barrier following the
// last read of the old contents (sB[b] read only at its quadrant-0 phase; sA[b]
// read through its 4th phase). vmcnt(4) leaves exactly the 2 youngest half-tiles
// (next deadline is 4+ phases away) in flight -- never drains to 0 in the loop.
#define BM 256
#define BN 256
#define BK 64

#define STAGE_A(bufi, h, kt)                                                        \
    do {                                                                            \
        gload_lds16(gA + (size_t)((h) * 128) * DIN + (kt),                          \
                    &sA[bufi][(h) * 8192 + wave * 1024]);                           \
        gload_lds16(gA + (size_t)((h) * 128 + 8) * DIN + (kt),                      \
                    &sA[bufi][(h) * 8192 + wave * 1024 + 512]);                     \
    } while (0)

#define STAGE_B(bufi, h, kt)                                                        \
    do {                                                                            \
        gload_lds16(gB + (size_t)((h) * 128) * DIN + (kt),                          \
                    &sB[bufi][(h) * 8192 + wave * 1024]);                           \
        gload_lds16(gB + (size_t)((h) * 128 + 8) * DIN + (kt),                      \
                    &sB[bufi][(h) * 8192 + wave * 1024 + 512]);                     \
    } while (0)

#define PH(BUFI, QD, STG, TAIL)                                                     \
    {                                                                               \
        if ((QD) == 0) {                                                            \
            _Pragma("unroll") for (int ni = 0; ni < 4; ++ni) {                      \
                bfr[ni][0] = *(const bf16x8*)&sB[BUFI][rowB + ni * 1024 + q80];     \
                bfr[ni][1] = *(const bf16x8*)&sB[BUFI][rowB + ni * 1024 + q81];     \
            }                                                                       \
        }                                                                           \
        bf16x8 af[2][2];                                                            \
        _Pragma("unroll") for (int m2 = 0; m2 < 2; ++m2) {                          \
            af[m2][0] = *(const bf16x8*)&sA[BUFI][rowA + ((QD)*2 + m2) * 1024 + q80];\
            af[m2][1] = *(const bf16x8*)&sA[BUFI][rowA + ((QD)*2 + m2) * 1024 + q81];\
        }                                                                           \
        STG;                                                                        \
        __builtin_amdgcn_s_barrier();                                               \
        asm volatile("s_waitcnt lgkmcnt(0)" ::: "memory");                          \
        __builtin_amdgcn_s_setprio(1);                                              \
        _Pragma("unroll") for (int ks = 0; ks < 2; ++ks)                            \
            _Pragma("unroll") for (int m2 = 0; m2 < 2; ++m2)                        \
                _Pragma("unroll") for (int ni = 0; ni < 4; ++ni)                    \
                    acc[(QD)*2 + m2][ni] = __builtin_amdgcn_mfma_f32_16x16x32_bf16( \
                        af[m2][ks], bfr[ni][ks], acc[(QD)*2 + m2][ni], 0, 0, 0);    \
        __builtin_amdgcn_s_setprio(0);                                              \
        TAIL;                                                                       \
        __builtin_amdgcn_s_barrier();                                               \
    }

__global__ __launch_bounds__(512, 2) void gemm_bt(
    const unsigned short* __restrict__ A,   // [M][K] bf16
    const unsigned short* __restrict__ B,   // [N][K] bf16 (W transposed)
    float* __restrict__ C) {                // [M][N] fp32
    const int K = DIN, N = DOUT;

    __shared__ __align__(16) unsigned short sA[2][BM * BK];  // 2 x 32 KB
    __shared__ __align__(16) unsigned short sB[2][BN * BK];  // 2 x 32 KB

    const int tid  = threadIdx.x;
    const int wave = tid >> 6;
    const int lane = tid & 63;
    const int wm = wave >> 2;               // 0..1  (M)
    const int wn = wave & 3;                // 0..3  (N)

    // ---- staging addressing: wave w stages rows 16w..16w+15 of each half ----
    const int lrow = lane >> 3;             // 0..7 row within 8-row chunk
    const int qsrc = (lane & 7) ^ lrow;     // pre-swizzled global k-quad
    const unsigned short* gA =
        A + (size_t)(blockIdx.y * BM + wave * 16 + lrow) * K + qsrc * 8;
    const unsigned short* gB =
        B + (size_t)(blockIdx.x * BN + wave * 16 + lrow) * K + qsrc * 8;

    // ---- fragment read addressing (swizzled ds_read) ----
    const int mrow = lane & 15;
    const int kgrp = lane >> 4;             // 0..3
    const int xr   = lane & 7;              // = row&7 of the frag row
    const int q80  = ((kgrp ^ xr) << 3);        // ks=0 swizzled quad * 8
    const int q81  = (((4 | kgrp) ^ xr) << 3);  // ks=1
    const int rowA = (wm * 128 + mrow) << 6;    // *64 elems/row
    const int rowB = (wn * 64 + mrow) << 6;

    f32x4 acc[8][4];
#pragma unroll
    for (int i = 0; i < 8; ++i)
#pragma unroll
        for (int j = 0; j < 4; ++j) {
            f32x4 z = {0.f, 0.f, 0.f, 0.f};
            acc[i][j] = z;
        }
    bf16x8 bfr[4][2];                       // B-frags live across a K-tile's phases

    // ---- prologue: tile0 (A+B) + tile1 B; leave tile1 B in flight ----
    STAGE_A(0, 0, 0);
    STAGE_A(0, 1, 0);
    STAGE_B(0, 0, 0);
    STAGE_B(0, 1, 0);
    STAGE_B(1, 0, 64);
    STAGE_B(1, 1, 64);
    asm volatile("s_waitcnt vmcnt(4)" ::: "memory");
    __builtin_amdgcn_s_barrier();

    for (int kt = 0; kt < K; kt += 128) {
        const bool last = (kt + 128 >= K);
        PH(0, 0, STAGE_A(1, 0, kt + 64), )
        PH(0, 1, STAGE_A(1, 1, kt + 64), )
        PH(0, 2, if (!last) STAGE_B(0, 0, kt + 128), )
        PH(0, 3, if (!last) STAGE_B(0, 1, kt + 128),
                 if (last) asm volatile("s_waitcnt vmcnt(0)" ::: "memory");
                 else      asm volatile("s_waitcnt vmcnt(4)" ::: "memory"))
        PH(1, 0, if (!last) STAGE_A(0, 0, kt + 128), )
        PH(1, 1, if (!last) STAGE_A(0, 1, kt + 128), )
        PH(1, 2, if (!last) STAGE_B(1, 0, kt + 192), )
        PH(1, 3, if (!last) STAGE_B(1, 1, kt + 192),
                 if (!last) asm volatile("s_waitcnt vmcnt(4)" ::: "memory"))
    }

    // ---- epilogue: C/D layout col=lane&15, row=(lane>>4)*4+reg ----
    float* Cw = C + (size_t)(blockIdx.y * BM + wm * 128 + kgrp * 4) * N
                + (size_t)(blockIdx.x * BN + wn * 64 + mrow);
#pragma unroll
    for (int mi = 0; mi < 8; ++mi)
#pragma unroll
        for (int ni = 0; ni < 4; ++ni)
#pragma unroll
            for (int r = 0; r < 4; ++r)
                Cw[(size_t)(mi * 16 + r) * N + ni * 16] = acc[mi][ni][r];
}

// ============ safety-net fallback if ws is too small (slow but correct) ============
__global__ void gemm_naive(const float* __restrict__ x, const int* __restrict__ W,
                           float* __restrict__ out) {
    int n = blockIdx.x * blockDim.x + threadIdx.x;
    int t = blockIdx.y;
    const float* xr = x + (size_t)t * DIN;
    float acc = 0.f;
    for (int k = 0; k < DIN; ++k)
        acc += xr[k] * (float)W[(size_t)k * DOUT + n];
    out[(size_t)t * DOUT + n] = acc;
}

extern "C" void kernel_launch(void* const* d_in, const int* in_sizes, int n_in,
                              void* d_out, int out_size, void* d_ws, size_t ws_size,
                              hipStream_t stream) {
    const float* x = (const float*)d_in[0];
    const int*   W = (const int*)d_in[1];
    float* out = (float*)d_out;

    const size_t xb_elems = (size_t)TOKENS * DIN;           // 64 MB bf16
    const size_t wt_elems = (size_t)DIN * DOUT;             // 32 MB bf16
    const size_t need = (xb_elems + wt_elems) * sizeof(unsigned short);

    if (ws_size < need) {   // should not happen; correctness safety net
        dim3 g(DOUT / 256, TOKENS);
        gemm_naive<<<g, 256, 0, stream>>>(x, W, out);
        return;
    }

    unsigned short* xb = (unsigned short*)d_ws;
    unsigned short* Wt = xb + xb_elems;

    fused_cvt<<<WBLKS + XBLKS, 256, 0, stream>>>(x, W, xb, Wt);

    dim3 grid(DOUT / BN, TOKENS / BM);   // (16, 32)
    gemm_bt<<<grid, 512, 0, stream>>>(xb, Wt, out);
}

// Round 2
// 493.101 us; speedup vs baseline: 1.3156x; 1.0133x over previous
//
#include <hip/hip_runtime.h>
#include <stdint.h>

// Problem dims (fixed by reference)
#define TOKENS 8192
#define DIN    4096
#define DOUT   4096

typedef short bf16x8 __attribute__((ext_vector_type(8)));  // 8 bf16 = 4 VGPRs
typedef float f32x4  __attribute__((ext_vector_type(4)));  // MFMA 16x16 accum

// ---- fp32 -> bf16 round-to-nearest-even (inputs finite) ----
__device__ __forceinline__ unsigned short f2bf(float f) {
    union { float f; unsigned int u; } v; v.f = f;
    return (unsigned short)((v.u + 0x7fffu + ((v.u >> 16) & 1u)) >> 16);
}

// ---- ternary int {-1,0,1} -> bf16 bit pattern (2 selects, no float math) ----
__device__ __forceinline__ unsigned short tern2bf(int v) {
    return v == 0 ? (unsigned short)0u
                  : (v > 0 ? (unsigned short)0x3F80u : (unsigned short)0xBF80u);
}

// ---- async global->LDS, 16B/lane; LDS dest = wave-uniform base + lane*16 ----
__device__ __forceinline__ void gload_lds16(const unsigned short* g, unsigned short* l) {
    __builtin_amdgcn_global_load_lds(
        (const __attribute__((address_space(1))) unsigned int*)g,
        (__attribute__((address_space(3))) unsigned int*)l,
        16, 0, 0);
}

// ================= fused prologue: one kernel, two jobs =================
// blocks [0, 1024):   W int32 [K][N] -> Wt bf16 [N][K], 256k x 64n LDS tiles.
// blocks [1024, 3072): x fp32 -> bf16, 2x float4 in -> 1x 16B store out.
#define WBLKS 1024
#define XBLKS 2048

__global__ __launch_bounds__(256) void fused_cvt(
    const float* __restrict__ x, const int* __restrict__ W,
    unsigned short* __restrict__ xb, unsigned short* __restrict__ Wt) {
    __shared__ unsigned short lds[64][264];   // [n_local][k_local], pitch 264
    const int t = threadIdx.x;

    if (blockIdx.x < WBLKS) {
        // ---- W transpose part: tile k0..k0+255, n0..n0+63 ----
        const int b  = blockIdx.x;
        const int k0 = (b >> 6) * 256;        // 16 k-tiles
        const int n0 = (b & 63) * 64;         // 64 n-tiles
        const int nl = 4 * (t & 15);          // n_local base this thread fills
#pragma unroll
        for (int it = 0; it < 16; ++it) {
            const int r = (t >> 4) + 16 * it; // k_local
            int4 v = *(const int4*)&W[(size_t)(k0 + r) * DOUT + n0 + nl];
            lds[nl + 0][r] = tern2bf(v.x);
            lds[nl + 1][r] = tern2bf(v.y);
            lds[nl + 2][r] = tern2bf(v.z);
            lds[nl + 3][r] = tern2bf(v.w);
        }
        __syncthreads();
        const int n = t >> 2;                 // 0..63
        const int s = t & 3;
        unsigned short* drow = Wt + (size_t)(n0 + n) * DIN + k0;
#pragma unroll
        for (int u = 0; u < 8; ++u) {
            const int k = u * 32 + s * 8;     // lanes 0-3 cover 64B contiguous
            *(uint4*)&drow[k] = *(const uint4*)&lds[n][k];
        }
    } else {
        // ---- x convert part: 8 chunks of 8 floats per thread ----
        const int b2 = blockIdx.x - WBLKS;    // 0..2047
        const int stride = XBLKS * 256;       // chunks per sweep
        int c = b2 * 256 + t;
        const float4* x4 = (const float4*)x;
        uint4* o = (uint4*)xb;                // 8 bf16 = 16B per chunk
#pragma unroll
        for (int j = 0; j < 8; ++j, c += stride) {
            float4 a = x4[2 * c];
            float4 bvec = x4[2 * c + 1];
            uint4 p;
            p.x = (unsigned)f2bf(a.x)    | ((unsigned)f2bf(a.y) << 16);
            p.y = (unsigned)f2bf(a.z)    | ((unsigned)f2bf(a.w) << 16);
            p.z = (unsigned)f2bf(bvec.x) | ((unsigned)f2bf(bvec.y) << 16);
            p.w = (unsigned)f2bf(bvec.z) | ((unsigned)f2bf(bvec.w) << 16);
            o[c] = p;
        }
    }
}

// ================= main GEMM: 256x256 tile, BK=64, 8-phase schedule =================
// C[M][N] = A[M][K] * Bt[N][K]^T, bf16 inputs, fp32 accum.
// 512 threads = 8 waves (2M x 4N); each wave owns a 128x64 output tile
// (8 M-frags x 4 N-frags of 16x16, acc = 32 x f32x4 = 128 regs).
// LDS: sA[2][256][64] + sB[2][256][64] bf16 = 128 KiB (double-buffered K-tiles).
//
// LDS swizzle (T2, both-sides): linear LDS slot (row, q') holds global k-quad
// q = q' ^ (row&7); staging pre-swizzles the GLOBAL source per lane (gload_lds
// dest stays linear), ds_read applies the same XOR. R1 measured: 0 conflicts.
//
// 8 phases per loop iter = 2 K-tiles. Staging ledger (half-tile = 2 gloads/wave):
//   p0: sA[1].h0 @kt+64   p1: sA[1].h1 @kt+64
//   p2: sB[0].h0 @kt+128  p3: sB[0].h1 @kt+128 + vmcnt(4)
//   p4: sA[0].h0 @kt+128  p5: sA[0].h1 @kt+128
//   p6: sB[1].h0 @kt+192  p7: sB[1].h1 @kt+192 + vmcnt(4)
// vmcnt(4) leaves the youngest 2 half-tiles in flight (deadline 4+ phases away);
// never drains to 0 in the main loop. Last iteration is PEELED (R2): main loop
// runs kt=0..K-256 branch-free; the final iter stages only sA[1]@K-64 and drains.
#define BM 256
#define BN 256
#define BK 64

#define STAGE_A(bufi, h, kt)                                                        \
    do {                                                                            \
        gload_lds16(gA + (size_t)((h) * 128) * DIN + (kt),                          \
                    &sA[bufi][(h) * 8192 + wave * 1024]);                           \
        gload_lds16(gA + (size_t)((h) * 128 + 8) * DIN + (kt),                      \
                    &sA[bufi][(h) * 8192 + wave * 1024 + 512]);                     \
    } while (0)

#define STAGE_B(bufi, h, kt)                                                        \
    do {                                                                            \
        gload_lds16(gB + (size_t)((h) * 128) * DIN + (kt),                          \
                    &sB[bufi][(h) * 8192 + wave * 1024]);                           \
        gload_lds16(gB + (size_t)((h) * 128 + 8) * DIN + (kt),                      \
                    &sB[bufi][(h) * 8192 + wave * 1024 + 512]);                     \
    } while (0)

#define PH(BUFI, QD, STG, TAIL)                                                     \
    {                                                                               \
        if ((QD) == 0) {                                                            \
            _Pragma("unroll") for (int ni = 0; ni < 4; ++ni) {                      \
                bfr[ni][0] = *(const bf16x8*)&sB[BUFI][rowB + ni * 1024 + q80];     \
                bfr[ni][1] = *(const bf16x8*)&sB[BUFI][rowB + ni * 1024 + q81];     \
            }                                                                       \
        }                                                                           \
        bf16x8 af[2][2];                                                            \
        _Pragma("unroll") for (int m2 = 0; m2 < 2; ++m2) {                          \
            af[m2][0] = *(const bf16x8*)&sA[BUFI][rowA + ((QD)*2 + m2) * 1024 + q80];\
            af[m2][1] = *(const bf16x8*)&sA[BUFI][rowA + ((QD)*2 + m2) * 1024 + q81];\
        }                                                                           \
        STG;                                                                        \
        __builtin_amdgcn_s_barrier();                                               \
        asm volatile("s_waitcnt lgkmcnt(0)" ::: "memory");                          \
        __builtin_amdgcn_s_setprio(1);                                              \
        _Pragma("unroll") for (int ks = 0; ks < 2; ++ks)                            \
            _Pragma("unroll") for (int m2 = 0; m2 < 2; ++m2)                        \
                _Pragma("unroll") for (int ni = 0; ni < 4; ++ni)                    \
                    acc[(QD)*2 + m2][ni] = __builtin_amdgcn_mfma_f32_16x16x32_bf16( \
                        af[m2][ks], bfr[ni][ks], acc[(QD)*2 + m2][ni], 0, 0, 0);    \
        __builtin_amdgcn_s_setprio(0);                                              \
        TAIL;                                                                       \
        __builtin_amdgcn_s_barrier();                                               \
    }

#define VM4 asm volatile("s_waitcnt vmcnt(4)" ::: "memory")
#define VM0 asm volatile("s_waitcnt vmcnt(0)" ::: "memory")

__global__ __launch_bounds__(512, 2) void gemm_bt(
    const unsigned short* __restrict__ A,   // [M][K] bf16
    const unsigned short* __restrict__ B,   // [N][K] bf16 (W transposed)
    float* __restrict__ C) {                // [M][N] fp32
    const int K = DIN, N = DOUT;

    __shared__ __align__(16) unsigned short sA[2][BM * BK];  // 2 x 32 KB
    __shared__ __align__(16) unsigned short sB[2][BN * BK];  // 2 x 32 KB

    const int tid  = threadIdx.x;
    const int wave = tid >> 6;
    const int lane = tid & 63;
    const int wm = wave >> 2;               // 0..1  (M)
    const int wn = wave & 3;                // 0..3  (N)

    // ---- T1: XCD-aware bijective block swizzle (512 wgs, 8 XCDs, 64/XCD) ----
    // XCD i owns a compact 8x8 tile region -> per-K-step L2 working set ~384 KB.
    const int wg  = blockIdx.x + gridDim.x * blockIdx.y;   // hardware linear id
    const int xcd = wg & 7;
    const int idx = wg >> 3;                               // 0..63 within XCD
    const int bx  = (xcd & 1) * 8 + (idx & 7);             // 0..15  (N tiles)
    const int by  = (xcd >> 1) * 8 + (idx >> 3);           // 0..31  (M tiles)

    // ---- staging addressing: wave w stages rows 16w..16w+15 of each half ----
    const int lrow = lane >> 3;             // 0..7 row within 8-row chunk
    const int qsrc = (lane & 7) ^ lrow;     // pre-swizzled global k-quad
    const unsigned short* gA =
        A + (size_t)(by * BM + wave * 16 + lrow) * K + qsrc * 8;
    const unsigned short* gB =
        B + (size_t)(bx * BN + wave * 16 + lrow) * K + qsrc * 8;

    // ---- fragment read addressing (swizzled ds_read) ----
    const int mrow = lane & 15;
    const int kgrp = lane >> 4;             // 0..3
    const int xr   = lane & 7;              // = row&7 of the frag row
    const int q80  = ((kgrp ^ xr) << 3);        // ks=0 swizzled quad * 8
    const int q81  = (((4 | kgrp) ^ xr) << 3);  // ks=1
    const int rowA = (wm * 128 + mrow) << 6;    // *64 elems/row
    const int rowB = (wn * 64 + mrow) << 6;

    f32x4 acc[8][4];
#pragma unroll
    for (int i = 0; i < 8; ++i)
#pragma unroll
        for (int j = 0; j < 4; ++j) {
            f32x4 z = {0.f, 0.f, 0.f, 0.f};
            acc[i][j] = z;
        }
    bf16x8 bfr[4][2];                       // B-frags live across a K-tile's phases

    // ---- prologue: tile0 (A+B) + tile1 B; leave tile1 B in flight ----
    STAGE_A(0, 0, 0);
    STAGE_A(0, 1, 0);
    STAGE_B(0, 0, 0);
    STAGE_B(0, 1, 0);
    STAGE_B(1, 0, 64);
    STAGE_B(1, 1, 64);
    VM4;
    __builtin_amdgcn_s_barrier();

    // ---- main loop: 31 branch-free iterations (kt = 0 .. K-256) ----
    for (int kt = 0; kt + 256 <= K; kt += 128) {
        PH(0, 0, STAGE_A(1, 0, kt + 64), )
        PH(0, 1, STAGE_A(1, 1, kt + 64), )
        PH(0, 2, STAGE_B(0, 0, kt + 128), )
        PH(0, 3, STAGE_B(0, 1, kt + 128), VM4)
        PH(1, 0, STAGE_A(0, 0, kt + 128), )
        PH(1, 1, STAGE_A(0, 1, kt + 128), )
        PH(1, 2, STAGE_B(1, 0, kt + 192), )
        PH(1, 3, STAGE_B(1, 1, kt + 192), VM4)
    }

    // ---- peeled final iteration (kt = K-128): stage only sA[1]@K-64, drain ----
    {
        const int kt = K - 128;
        PH(0, 0, STAGE_A(1, 0, kt + 64), )
        PH(0, 1, STAGE_A(1, 1, kt + 64), )
        PH(0, 2, , )
        PH(0, 3, , VM0)
        PH(1, 0, , )
        PH(1, 1, , )
        PH(1, 2, , )
        PH(1, 3, , )
    }

    // ---- epilogue: C/D layout col=lane&15, row=(lane>>4)*4+reg ----
    // Nontemporal: C is write-once; streaming it keeps xb+Wt L3-resident.
    float* Cw = C + (size_t)(by * BM + wm * 128 + kgrp * 4) * N
                + (size_t)(bx * BN + wn * 64 + mrow);
#pragma unroll
    for (int mi = 0; mi < 8; ++mi)
#pragma unroll
        for (int ni = 0; ni < 4; ++ni)
#pragma unroll
            for (int r = 0; r < 4; ++r)
                __builtin_nontemporal_store(acc[mi][ni][r],
                                            &Cw[(size_t)(mi * 16 + r) * N + ni * 16]);
}

// ============ safety-net fallback if ws is too small (slow but correct) ============
__global__ void gemm_naive(const float* __restrict__ x, const int* __restrict__ W,
                           float* __restrict__ out) {
    int n = blockIdx.x * blockDim.x + threadIdx.x;
    int t = blockIdx.y;
    const float* xr = x + (size_t)t * DIN;
    float acc = 0.f;
    for (int k = 0; k < DIN; ++k)
        acc += xr[k] * (float)W[(size_t)k * DOUT + n];
    out[(size_t)t * DOUT + n] = acc;
}

extern "C" void kernel_launch(void* const* d_in, const int* in_sizes, int n_in,
                              void* d_out, int out_size, void* d_ws, size_t ws_size,
                              hipStream_t stream) {
    const float* x = (const float*)d_in[0];
    const int*   W = (const int*)d_in[1];
    float* out = (float*)d_out;

    const size_t xb_elems = (size_t)TOKENS * DIN;           // 64 MB bf16
    const size_t wt_elems = (size_t)DIN * DOUT;             // 32 MB bf16
    const size_t need = (xb_elems + wt_elems) * sizeof(unsigned short);

    if (ws_size < need) {   // should not happen; correctness safety net
        dim3 g(DOUT / 256, TOKENS);
        gemm_naive<<<g, 256, 0, stream>>>(x, W, out);
        return;
    }

    unsigned short* xb = (unsigned short*)d_ws;
    unsigned short* Wt = xb + xb_elems;

    fused_cvt<<<WBLKS + XBLKS, 256, 0, stream>>>(x, W, xb, Wt);

    dim3 grid(DOUT / BN, TOKENS / BM);   // (16, 32)
    gemm_bt<<<grid, 512, 0, stream>>>(xb, Wt, out);
}

// Round 3
// 487.456 us; speedup vs baseline: 1.3308x; 1.0116x over previous
//
#include <hip/hip_runtime.h>
#include <stdint.h>

// Problem dims (fixed by reference)
#define TOKENS 8192
#define DIN    4096
#define DOUT   4096

typedef short bf16x8 __attribute__((ext_vector_type(8)));  // 8 bf16 = 4 VGPRs
typedef float f32x4  __attribute__((ext_vector_type(4)));  // MFMA 16x16 accum

// ---- fp32 -> bf16 round-to-nearest-even (inputs finite) ----
__device__ __forceinline__ unsigned short f2bf(float f) {
    union { float f; unsigned int u; } v; v.f = f;
    return (unsigned short)((v.u + 0x7fffu + ((v.u >> 16) & 1u)) >> 16);
}

// ---- ternary int {-1,0,1} -> bf16 bit pattern (2 selects, no float math) ----
__device__ __forceinline__ unsigned short tern2bf(int v) {
    return v == 0 ? (unsigned short)0u
                  : (v > 0 ? (unsigned short)0x3F80u : (unsigned short)0xBF80u);
}

// ---- async global->LDS, 16B/lane; LDS dest = wave-uniform base + lane*16 ----
__device__ __forceinline__ void gload_lds16(const unsigned short* g, unsigned short* l) {
    __builtin_amdgcn_global_load_lds(
        (const __attribute__((address_space(1))) unsigned int*)g,
        (__attribute__((address_space(3))) unsigned int*)l,
        16, 0, 0);
}

// ================= fused prologue: one kernel, two jobs =================
#define WBLKS 1024
#define XBLKS 2048

__global__ __launch_bounds__(256) void fused_cvt(
    const float* __restrict__ x, const int* __restrict__ W,
    unsigned short* __restrict__ xb, unsigned short* __restrict__ Wt) {
    __shared__ unsigned short lds[64][264];   // [n_local][k_local], pitch 264
    const int t = threadIdx.x;

    if (blockIdx.x < WBLKS) {
        // ---- W transpose part: tile k0..k0+255, n0..n0+63 ----
        const int b  = blockIdx.x;
        const int k0 = (b >> 6) * 256;        // 16 k-tiles
        const int n0 = (b & 63) * 64;         // 64 n-tiles
        const int nl = 4 * (t & 15);          // n_local base this thread fills
#pragma unroll
        for (int it = 0; it < 16; ++it) {
            const int r = (t >> 4) + 16 * it; // k_local
            int4 v = *(const int4*)&W[(size_t)(k0 + r) * DOUT + n0 + nl];
            lds[nl + 0][r] = tern2bf(v.x);
            lds[nl + 1][r] = tern2bf(v.y);
            lds[nl + 2][r] = tern2bf(v.z);
            lds[nl + 3][r] = tern2bf(v.w);
        }
        __syncthreads();
        const int n = t >> 2;                 // 0..63
        const int s = t & 3;
        unsigned short* drow = Wt + (size_t)(n0 + n) * DIN + k0;
#pragma unroll
        for (int u = 0; u < 8; ++u) {
            const int k = u * 32 + s * 8;     // lanes 0-3 cover 64B contiguous
            *(uint4*)&drow[k] = *(const uint4*)&lds[n][k];
        }
    } else {
        // ---- x convert part: 8 chunks of 8 floats per thread ----
        const int b2 = blockIdx.x - WBLKS;    // 0..2047
        const int stride = XBLKS * 256;       // chunks per sweep
        int c = b2 * 256 + t;
        const float4* x4 = (const float4*)x;
        uint4* o = (uint4*)xb;                // 8 bf16 = 16B per chunk
#pragma unroll
        for (int j = 0; j < 8; ++j, c += stride) {
            float4 a = x4[2 * c];
            float4 bvec = x4[2 * c + 1];
            uint4 p;
            p.x = (unsigned)f2bf(a.x)    | ((unsigned)f2bf(a.y) << 16);
            p.y = (unsigned)f2bf(a.z)    | ((unsigned)f2bf(a.w) << 16);
            p.z = (unsigned)f2bf(bvec.x) | ((unsigned)f2bf(bvec.y) << 16);
            p.w = (unsigned)f2bf(bvec.z) | ((unsigned)f2bf(bvec.w) << 16);
            o[c] = p;
        }
    }
}

// ================= main GEMM: 256x256 tile, BK=64, pipelined 8-phase =================
// R3 restructure: reads-ahead-1 software pipeline, ONE barrier per phase.
// Phase body: [issue af-reads for NEXT phase] [STAGE] [counted vmcnt where due]
//             [s_barrier] [setprio(1) MFMA on frags read LAST phase setprio(0)]
// A-frag LDS drain overlaps the MFMA window; compiler emits counted lgkmcnt
// before each consuming MFMA (C-level LDS loads -> dependency tracked).
// B-frags (bfr) read at their K-tile's first phase (2 exposed bursts/iter).
//
// WAR rule (1 barrier/phase): STG(buf X) issue must follow BARRIER(r+1), where
// r = phase that ISSUED the last reads of old X:
//   B0: r=p0 -> STG @p2/p3 OK   A0: r=p2 -> STG @p4/p5 OK
//   B1: r=p4 -> STG @p6/p7 OK   A1: r=p6 -> STG @next p0/p1 OK
// RAW (vmcnt, counted, never 0 in loop):
//   p3: STG;VM4 -> drains A1@kt+64 (p0/p1) + B1@kt+64 (prev p6/p7), leaves
//       B0@kt+128 (p2/p3) in flight; then af0(buf1) reads are safe.
//   p7: STG;VM4 -> drains B0/A0@kt+128, leaves B1@kt+192; af0(buf0-next) safe.
// Prologue leaves B1@64 (4 loads) outstanding = steady-state entry condition.
#define BM 256
#define BN 256
#define BK 64

#define STAGE_A(bufi, h, kt)                                                        \
    do {                                                                            \
        gload_lds16(gA + (size_t)((h) * 128) * DIN + (kt),                          \
                    &sA[bufi][(h) * 8192 + wave * 1024]);                           \
        gload_lds16(gA + (size_t)((h) * 128 + 8) * DIN + (kt),                      \
                    &sA[bufi][(h) * 8192 + wave * 1024 + 512]);                     \
    } while (0)

#define STAGE_B(bufi, h, kt)                                                        \
    do {                                                                            \
        gload_lds16(gB + (size_t)((h) * 128) * DIN + (kt),                          \
                    &sB[bufi][(h) * 8192 + wave * 1024]);                           \
        gload_lds16(gB + (size_t)((h) * 128 + 8) * DIN + (kt),                      \
                    &sB[bufi][(h) * 8192 + wave * 1024 + 512]);                     \
    } while (0)

// 4 ds_read_b128: A-frags for quadrant QD of buffer BUF into register set AF
#define RD_AF(AF, BUF, QD)                                                          \
    do {                                                                            \
        _Pragma("unroll") for (int m2 = 0; m2 < 2; ++m2) {                          \
            AF[m2][0] = *(const bf16x8*)&sA[BUF][rowA + ((QD)*2 + m2) * 1024 + q80];\
            AF[m2][1] = *(const bf16x8*)&sA[BUF][rowA + ((QD)*2 + m2) * 1024 + q81];\
        }                                                                           \
    } while (0)

// 8 ds_read_b128: all B-frags of buffer BUF (live across its 4 phases)
#define RD_BF(BUF)                                                                  \
    do {                                                                            \
        _Pragma("unroll") for (int ni = 0; ni < 4; ++ni) {                          \
            bfr[ni][0] = *(const bf16x8*)&sB[BUF][rowB + ni * 1024 + q80];          \
            bfr[ni][1] = *(const bf16x8*)&sB[BUF][rowB + ni * 1024 + q81];          \
        }                                                                           \
    } while (0)

// 16 MFMA: quadrant QD using A-set AF + resident bfr
#define MM(AF, QD)                                                                  \
    do {                                                                            \
        __builtin_amdgcn_s_setprio(1);                                              \
        _Pragma("unroll") for (int ks = 0; ks < 2; ++ks)                            \
            _Pragma("unroll") for (int m2 = 0; m2 < 2; ++m2)                        \
                _Pragma("unroll") for (int ni = 0; ni < 4; ++ni)                    \
                    acc[(QD)*2 + m2][ni] = __builtin_amdgcn_mfma_f32_16x16x32_bf16( \
                        AF[m2][ks], bfr[ni][ks], acc[(QD)*2 + m2][ni], 0, 0, 0);    \
        __builtin_amdgcn_s_setprio(0);                                              \
    } while (0)

#define BAR __builtin_amdgcn_s_barrier()
#define VM4 asm volatile("s_waitcnt vmcnt(4)" ::: "memory")
#define VM0 asm volatile("s_waitcnt vmcnt(0)" ::: "memory")

__global__ __launch_bounds__(512, 2) void gemm_bt(
    const unsigned short* __restrict__ A,   // [M][K] bf16
    const unsigned short* __restrict__ B,   // [N][K] bf16 (W transposed)
    float* __restrict__ C) {                // [M][N] fp32
    const int K = DIN, N = DOUT;

    __shared__ __align__(16) unsigned short sA[2][BM * BK];  // 2 x 32 KB
    __shared__ __align__(16) unsigned short sB[2][BN * BK];  // 2 x 32 KB

    const int tid  = threadIdx.x;
    const int wave = tid >> 6;
    const int lane = tid & 63;
    const int wm = wave >> 2;               // 0..1  (M)
    const int wn = wave & 3;                // 0..3  (N)

    // ---- T1: XCD-aware bijective block swizzle (512 wgs, 8 XCDs, 64/XCD) ----
    const int wg  = blockIdx.x + gridDim.x * blockIdx.y;   // hardware linear id
    const int xcd = wg & 7;
    const int idx = wg >> 3;                               // 0..63 within XCD
    const int bx  = (xcd & 1) * 8 + (idx & 7);             // 0..15  (N tiles)
    const int by  = (xcd >> 1) * 8 + (idx >> 3);           // 0..31  (M tiles)

    // ---- staging addressing: wave w stages rows 16w..16w+15 of each half ----
    const int lrow = lane >> 3;             // 0..7 row within 8-row chunk
    const int qsrc = (lane & 7) ^ lrow;     // pre-swizzled global k-quad
    const unsigned short* gA =
        A + (size_t)(by * BM + wave * 16 + lrow) * K + qsrc * 8;
    const unsigned short* gB =
        B + (size_t)(bx * BN + wave * 16 + lrow) * K + qsrc * 8;

    // ---- fragment read addressing (swizzled ds_read) ----
    const int mrow = lane & 15;
    const int kgrp = lane >> 4;             // 0..3
    const int xr   = lane & 7;              // = row&7 of the frag row
    const int q80  = ((kgrp ^ xr) << 3);        // ks=0 swizzled quad * 8
    const int q81  = (((4 | kgrp) ^ xr) << 3);  // ks=1
    const int rowA = (wm * 128 + mrow) << 6;    // *64 elems/row
    const int rowB = (wn * 64 + mrow) << 6;

    f32x4 acc[8][4];
#pragma unroll
    for (int i = 0; i < 8; ++i)
#pragma unroll
        for (int j = 0; j < 4; ++j) {
            f32x4 z = {0.f, 0.f, 0.f, 0.f};
            acc[i][j] = z;
        }
    bf16x8 bfr[4][2];     // B-frags: resident across a K-tile's 4 phases
    bf16x8 afA[2][2];     // A-frag double-buffer, set A (even phases' MFMA)
    bf16x8 afB[2][2];     // set B (odd phases' MFMA)

    // ---- prologue: tile0 A+B, tile1 B; leave B1@64 (4 loads) in flight ----
    STAGE_A(0, 0, 0);
    STAGE_A(0, 1, 0);
    STAGE_B(0, 0, 0);
    STAGE_B(0, 1, 0);
    STAGE_B(1, 0, 64);
    STAGE_B(1, 1, 64);
    VM4;                          // A0,B0 complete; B1 still flying
    BAR;
    RD_AF(afA, 0, 0);             // af for p0's MFMA (QD0, buf0)

    // ---- main loop: 31 iterations, 8 phases each, 1 barrier/phase ----
    for (int kt = 0; kt + 256 <= K; kt += 128) {
        // p0: MFMA QD0(buf0); bfr(buf0) read this phase (exposed burst)
        RD_BF(0);
        RD_AF(afB, 0, 1);
        STAGE_A(1, 0, kt + 64);
        BAR;  MM(afA, 0);
        // p1
        RD_AF(afA, 0, 2);
        STAGE_A(1, 1, kt + 64);
        BAR;  MM(afB, 1);
        // p2
        RD_AF(afB, 0, 3);
        STAGE_B(0, 0, kt + 128);
        BAR;  MM(afA, 2);
        // p3: VM4 drains A1@kt+64 (+older) before reading buf1
        STAGE_B(0, 1, kt + 128);
        VM4;
        RD_AF(afA, 1, 0);
        BAR;  MM(afB, 3);
        // p4: MFMA QD0(buf1); bfr(buf1) read this phase
        RD_BF(1);
        RD_AF(afB, 1, 1);
        STAGE_A(0, 0, kt + 128);
        BAR;  MM(afA, 0);
        // p5
        RD_AF(afA, 1, 2);
        STAGE_A(0, 1, kt + 128);
        BAR;  MM(afB, 1);
        // p6
        RD_AF(afB, 1, 3);
        STAGE_B(1, 0, kt + 192);
        BAR;  MM(afA, 2);
        // p7: VM4 drains A0/B0@kt+128 before reading buf0@next
        STAGE_B(1, 1, kt + 192);
        VM4;
        RD_AF(afA, 0, 0);
        BAR;  MM(afB, 3);
    }

    // ---- peeled final iteration (kt = K-128): stage only A1@K-64, drain ----
    {
        const int kt = K - 128;
        RD_BF(0);
        RD_AF(afB, 0, 1);
        STAGE_A(1, 0, kt + 64);
        BAR;  MM(afA, 0);

        RD_AF(afA, 0, 2);
        STAGE_A(1, 1, kt + 64);
        BAR;  MM(afB, 1);

        RD_AF(afB, 0, 3);
        BAR;  MM(afA, 2);

        VM0;                       // drain A1@K-64 + B1@K-64 (epilogue of pipe)
        RD_AF(afA, 1, 0);
        BAR;  MM(afB, 3);

        RD_BF(1);
        RD_AF(afB, 1, 1);
        BAR;  MM(afA, 0);

        RD_AF(afA, 1, 2);
        BAR;  MM(afB, 1);

        RD_AF(afB, 1, 3);
        BAR;  MM(afA, 2);

        MM(afB, 3);
    }

    // ---- epilogue: C/D layout col=lane&15, row=(lane>>4)*4+reg; NT stores ----
    float* Cw = C + (size_t)(by * BM + wm * 128 + kgrp * 4) * N
                + (size_t)(bx * BN + wn * 64 + mrow);
#pragma unroll
    for (int mi = 0; mi < 8; ++mi)
#pragma unroll
        for (int ni = 0; ni < 4; ++ni)
#pragma unroll
            for (int r = 0; r < 4; ++r)
                __builtin_nontemporal_store(acc[mi][ni][r],
                                            &Cw[(size_t)(mi * 16 + r) * N + ni * 16]);
}

// ============ safety-net fallback if ws is too small (slow but correct) ============
__global__ void gemm_naive(const float* __restrict__ x, const int* __restrict__ W,
                           float* __restrict__ out) {
    int n = blockIdx.x * blockDim.x + threadIdx.x;
    int t = blockIdx.y;
    const float* xr = x + (size_t)t * DIN;
    float acc = 0.f;
    for (int k = 0; k < DIN; ++k)
        acc += xr[k] * (float)W[(size_t)k * DOUT + n];
    out[(size_t)t * DOUT + n] = acc;
}

extern "C" void kernel_launch(void* const* d_in, const int* in_sizes, int n_in,
                              void* d_out, int out_size, void* d_ws, size_t ws_size,
                              hipStream_t stream) {
    const float* x = (const float*)d_in[0];
    const int*   W = (const int*)d_in[1];
    float* out = (float*)d_out;

    const size_t xb_elems = (size_t)TOKENS * DIN;           // 64 MB bf16
    const size_t wt_elems = (size_t)DIN * DOUT;             // 32 MB bf16
    const size_t need = (xb_elems + wt_elems) * sizeof(unsigned short);

    if (ws_size < need) {   // should not happen; correctness safety net
        dim3 g(DOUT / 256, TOKENS);
        gemm_naive<<<g, 256, 0, stream>>>(x, W, out);
        return;
    }

    unsigned short* xb = (unsigned short*)d_ws;
    unsigned short* Wt = xb + xb_elems;

    fused_cvt<<<WBLKS + XBLKS, 256, 0, stream>>>(x, W, xb, Wt);

    dim3 grid(DOUT / BN, TOKENS / BM);   // (16, 32)
    gemm_bt<<<grid, 512, 0, stream>>>(xb, Wt, out);
}